// Round 23
// baseline (48.285 us; speedup 1.0000x reference)
//
#include <hip/hip_runtime.h>
#include <math.h>

// DifferentiableLassoSelector: B=65536, n=256, h=32.
// p = 6553.6 - Z^T y > 0 elementwise (~40 sigma margin) => projected-gradient
// QP stays at lam=0 exactly => y_hat = 0 exactly.
// Chebyshev factorization, h pre-combined: C_k[n] = sum_h W2 c_k[n,h];
// z~[b,n] = sum_k C_k T_k(x/X); zty[n] = sum_b y z~.
// Config ledger: (4 blk/CU, 8-row chunks)=45.9; (2 blk/CU, 16-row)=47.7.
// r23 tests the unexplored quadrant: 4 blk/CU AND 16-row chunks --
// 1024 blocks x 64 rows, 4 chunks of 16 (32KB LDS dbuf, 128KB/CU fits).
// Barriers/block 8->4, compute/barrier x2, same grid & prologue as r21.
// Certification gates the zero path; exact fallback is one flag-guarded
// kernel (last-block-done ticket).

#define NF 256
#define HID 32
#define BATCHN 65536
#define ALPHA_BF 6553.6f               // ALPHA * BATCH
#define JITTERF 1e-4f
#define QP_ITERS_N 500
#define K2C 2.8853900817779268f        // 2*log2(e): exp2(K2C*u) = e^{2u}
#define XFIX 6.5f
#define INVX (1.0f / 6.5f)
#define NNODE 44                       // Chebyshev nodes; coeffs k=0..43
// ws float layout:
// 0: flagA | 1: Xobs bits | 2: ticket | 8..72: ypart[64] | 72..136: yabspart
// 256:     Carr[21][256]     -> 5632
// 5632:    tailpart[23][256] -> 11520
// 11520:   sw2[256]          -> 11776
// 12288:   part2[64][256]    -> 28672
// 28672:   part[1024][256]   -> 290816
// 552960:  fb_part[2048][256]-> 1077248
// 1077248: p_ex[256]         -> 1077504
// 1077504: Q | L | Qe        -> 1274112  (~5.1 MB total)

#if __has_builtin(__builtin_amdgcn_exp2f)
__device__ __forceinline__ float fexp2(float x) { return __builtin_amdgcn_exp2f(x); }
#else
__device__ __forceinline__ float fexp2(float x) { return exp2f(x); }
#endif
#if __has_builtin(__builtin_amdgcn_rcpf)
__device__ __forceinline__ float frcp(float x) { return __builtin_amdgcn_rcpf(x); }
#else
__device__ __forceinline__ float frcp(float x) { return 1.0f / x; }
#endif

// async global->LDS stage of 16B/lane (1KB/wave): LDS dest is wave-uniform,
// HW scatters lane l to ldst + l*16. Fallback: reg-relay with same layout.
#if __has_builtin(__builtin_amdgcn_global_load_lds)
#define STAGE_ROW(gsrc, ldst, lane) \
  __builtin_amdgcn_global_load_lds( \
      (const __attribute__((address_space(1))) void*)(gsrc), \
      (__attribute__((address_space(3))) void*)(ldst), 16, 0, 0)
#else
#define STAGE_ROW(gsrc, ldst, lane) \
  do { *reinterpret_cast<float4*>((float*)(ldst) + (lane) * 4) = \
       *reinterpret_cast<const float4*>(gsrc); } while (0)
#endif

// exact per-feature MLP output z[b,n] (fallback path only; perf-irrelevant)
__device__ __forceinline__ float zeval(const float* __restrict__ W1,
                                       const float* __restrict__ b1,
                                       const float* __restrict__ W2,
                                       const float* __restrict__ b2,
                                       int n, float xv)
{
  float acc = b2[n];
  for (int h = 0; h < HID; ++h) {
    float u  = fmaf(xv, W1[n * HID + h], b1[n * HID + h]);
    float th = fmaf(-2.f, frcp(fexp2(K2C * u) + 1.f), 1.f);   // exact tanh
    acc = fmaf(W2[n * HID + h], th, acc);
  }
  return acc;
}

// ---------------- mcoeff: ysum (blocks 0..63) + combined coeffs (64..1471) ---
__global__ __launch_bounds__(256) void mcoeff_kernel(
    const float* __restrict__ y,
    const float* __restrict__ W1, const float* __restrict__ b1,
    const float* __restrict__ W2, float* __restrict__ wsf)
{
  const int t = threadIdx.x;
  if ((int)blockIdx.x < 64) {
    // ---- ysum role: per-block partial sums of y and |y| ----
    const int gi = blockIdx.x * 256 + t;
    if (gi == 0) wsf[1] = 0.f;                  // Xobs (atomicMax target)
    if (gi == 2) wsf[2] = 0.f;                  // fallback ticket
    float4 v = *reinterpret_cast<const float4*>(y + gi * 4);
    float s  = (v.x + v.y) + (v.z + v.w);
    float sa = (fabsf(v.x) + fabsf(v.y)) + (fabsf(v.z) + fabsf(v.w));
    #pragma unroll
    for (int m = 1; m < 64; m <<= 1) {
      s  += __shfl_xor(s, m);
      sa += __shfl_xor(sa, m);
    }
    __shared__ float ls[4], la[4];
    int w = t >> 6;
    if ((t & 63) == 0) { ls[w] = s; la[w] = sa; }
    __syncthreads();
    if (t == 0) {
      wsf[8  + blockIdx.x] = (ls[0] + ls[1]) + (ls[2] + ls[3]);
      wsf[72 + blockIdx.x] = (la[0] + la[1]) + (la[2] + la[3]);
    }
  } else {
    // ---- coeff role: thread = (id, k); h-reduced combined coefficients ----
    const int cb = blockIdx.x - 64;            // [0, 1408)
    const int k  = cb >> 5;                    // 0..43
    const int id = (cb & 31) * 256 + t;        // 0..8191 = n*32+h
    const int h  = t & 31;
    const int n  = id >> 5;
    const float aX  = W1[id] * XFIX;
    const float bb  = b1[id];
    const float w2v = W2[id];
    const float kf = (float)k;
    const float C1 = (float)(M_PI / (double)NNODE);
    float acc = 0.f;
    #pragma unroll 4
    for (int jn = 0; jn < NNODE; ++jn) {
      float ang = ((float)jn + 0.5f) * C1;
      float tj  = __cosf(ang);
      float u   = fmaf(aX, tj, bb);
      float f   = fmaf(-2.f, frcp(fexp2(K2C * u) + 1.f), 1.f);  // exact tanh
      acc = fmaf(f, __cosf(kf * ang), acc);
    }
    const float ck = acc * ((k == 0) ? (1.0f / (float)NNODE)
                                     : (2.0f / (float)NNODE));
    float comb = w2v * ck;                     // signed, for C_k[n]
    float cabs = fabsf(comb);                  // |W2 c_k|, for tail
    float wabs = fabsf(w2v);                   // |W2|, for k==0 slack
    #pragma unroll
    for (int m = 1; m < 32; m <<= 1) {         // reduce over h (32 lanes)
      comb += __shfl_xor(comb, m);
      cabs += __shfl_xor(cabs, m);
      wabs += __shfl_xor(wabs, m);
    }
    if (h == 0) {
      if (k <= 20) wsf[256 + k * 256 + n] = comb;
      else         wsf[5632 + (k - 21) * 256 + n] = cabs;
      if (k == 0)  wsf[11520 + n] = wabs;
    }
  }
}

// ---------------- zmom: LDS-staged, 16-row chunks, 1024 blocks x 64 rows -----
#define STEP1(CK) { float q = fmaf(dd, Tc, -Tm); \
  a = fmaf(CK, q, a); Tm = Tc; Tc = q; }

__global__ __launch_bounds__(256, 4) void zmom_kernel(
    const float* __restrict__ x, const float* __restrict__ y,
    float* __restrict__ wsf)
{
  const int t = threadIdx.x;                // feature n == t
  const int lane = t & 63, wv = t >> 6;
  __shared__ float xbuf[2][16][NF];         // 32 KB: 2 bufs x 16 rows x 1KB
  const float* Carr = wsf + 256;
  const float c00 = Carr[t],            c01 = Carr[256 + t];
  const float c02 = Carr[512 + t],      c03 = Carr[768 + t];
  const float c04 = Carr[1024 + t],     c05 = Carr[1280 + t];
  const float c06 = Carr[1536 + t],     c07 = Carr[1792 + t];
  const float c08 = Carr[2048 + t],     c09 = Carr[2304 + t];
  const float c10 = Carr[2560 + t],     c11 = Carr[2816 + t];
  const float c12 = Carr[3072 + t],     c13 = Carr[3328 + t];
  const float c14 = Carr[3584 + t],     c15 = Carr[3840 + t];
  const float c16 = Carr[4096 + t],     c17 = Carr[4352 + t];
  const float c18 = Carr[4608 + t],     c19 = Carr[4864 + t];
  const float c20 = Carr[5120 + t];
  const int b0 = blockIdx.x * 64;           // 1024 blocks x 64 rows
  // prologue: wave wv stages rows {4wv..4wv+3} of chunk 0 (4 instr = 4KB)
  #pragma unroll
  for (int q = 0; q < 4; ++q)
    STAGE_ROW(x + (size_t)(b0 + 4 * wv + q) * NF + lane * 4,
              &xbuf[0][4 * wv + q][0], lane);
  __syncthreads();                          // drains vmcnt -> buf0 ready
  float z0 = 0.f, mx = 0.f;
  for (int c = 0; c < 4; ++c) {             // 4 chunks x 16 rows
    if (c < 3) {
      const int r0 = b0 + (c + 1) * 16 + 4 * wv;
      #pragma unroll
      for (int q = 0; q < 4; ++q)
        STAGE_ROW(x + (size_t)(r0 + q) * NF + lane * 4,
                  &xbuf[(c + 1) & 1][4 * wv + q][0], lane);
    }
    const float* xb = &xbuf[c & 1][0][0];
    const float* yb = y + b0 + c * 16;
    #pragma unroll
    for (int r = 0; r < 16; ++r) {          // 16 independent rows (ILP)
      float xv = xb[r * NF + t];            // ds_read, 2-way bank = free
      float yv = yb[r];                     // uniform -> scalar load
      mx = fmaxf(mx, fabsf(xv));
      float h = xv * INVX;
      float dd = h + h;
      float Tm = 1.f, Tc = h;
      float a = fmaf(c01, h, c00);
      STEP1(c02) STEP1(c03) STEP1(c04) STEP1(c05) STEP1(c06) STEP1(c07)
      STEP1(c08) STEP1(c09) STEP1(c10) STEP1(c11) STEP1(c12) STEP1(c13)
      STEP1(c14) STEP1(c15) STEP1(c16) STEP1(c17) STEP1(c18) STEP1(c19)
      STEP1(c20)
      z0 = fmaf(a, yv, z0);
    }
    __syncthreads();                        // drains next-chunk stage + sync
  }
  // |x| max: wave-reduce, block-reduce, ONE atomic per block (order-exact)
  #pragma unroll
  for (int m = 1; m < 64; m <<= 1) mx = fmaxf(mx, __shfl_xor(mx, m));
  __shared__ float wmx[4];
  if (lane == 0) wmx[wv] = mx;
  __syncthreads();
  if (t == 0) {
    float m4 = fmaxf(fmaxf(wmx[0], wmx[1]), fmaxf(wmx[2], wmx[3]));
    atomicMax(reinterpret_cast<unsigned int*>(&wsf[1]), __float_as_uint(m4));
  }
  wsf[28672 + (size_t)blockIdx.x * NF + t] = z0;  // coalesced 1KB/blk
}

// ---------------- red1f: part[1024][256] -> part2[64][256] -------------------
__global__ __launch_bounds__(256) void red1f_kernel(float* __restrict__ wsf)
{
  const int n = threadIdx.x, j = blockIdx.x;      // 64 blocks x 16 slices
  const float* p = wsf + 28672 + (size_t)j * 16 * NF + n;
  float s0 = 0.f, s1 = 0.f, s2 = 0.f, s3 = 0.f;
  #pragma unroll
  for (int k = 0; k < 16; k += 4) {
    s0 += p[(size_t)k * NF];       s1 += p[(size_t)(k + 1) * NF];
    s2 += p[(size_t)(k + 2) * NF]; s3 += p[(size_t)(k + 3) * NF];
  }
  wsf[12288 + (size_t)j * NF + n] = (s0 + s1) + (s2 + s3);
}

// ---------------- zwflag: redundant flag computation + zero-write ------------
__global__ __launch_bounds__(256) void zwflag_kernel(
    const float* __restrict__ b2, float* __restrict__ wsf,
    float* __restrict__ out)
{
  const int t = threadIdx.x;                      // t == feature n
  __shared__ float shv[2];
  if (t < 64) {
    float a = wsf[8 + t], bb = wsf[72 + t];
    #pragma unroll
    for (int m = 1; m < 64; m <<= 1) {
      a  += __shfl_xor(a, m);
      bb += __shfl_xor(bb, m);
    }
    if (t == 0) { shv[0] = a; shv[1] = bb; }
  }
  __syncthreads();
  const float Sy = shv[0], SyA = shv[1];
  float s = 0.f;
  #pragma unroll
  for (int j = 0; j < 64; ++j) s += wsf[12288 + j * NF + t];
  float tailn = 0.f;
  #pragma unroll
  for (int q = 0; q < 23; ++q) tailn += wsf[5632 + q * 256 + t];
  float ptil = ALPHA_BF - (s + b2[t] * Sy);
  float cert = fmaf(fmaf(3.0f, tailn, 3e-3f * wsf[11520 + t]), SyA, 128.0f);
  int ok = ((ptil - cert) >= 0.f) ? 1 : 0;        // NaN -> 0
  __shared__ int smi[256];
  __shared__ int okk;
  smi[t] = ok;
  __syncthreads();
  for (int off = 128; off > 0; off >>= 1) {
    if (t < off) smi[t] = smi[t] & smi[t + off];
    __syncthreads();
  }
  if (t == 0) {
    float Xo = __uint_as_float(*reinterpret_cast<unsigned int*>(&wsf[1]));
    okk = (smi[0] && (Xo <= XFIX)) ? 1 : 0;
    if (blockIdx.x == 0) wsf[0] = okk ? 1.f : 0.f;   // flag for fallback
  }
  __syncthreads();
  if (!okk) return;
  int i = blockIdx.x * 256 + t;                   // 257 blocks = 65792 exactly
  if (i < BATCHN + NF) out[i] = 0.f;              // exact zeros
}

// ---------------- fb_all: entire exact fallback in ONE node ------------------
// flag==1 (always, for bench inputs): every block exits immediately.
// flag==0: 2048 blocks compute exact zty partials; the LAST block to finish
// (device-scope ticket) serially completes p, Q, Cholesky, QP, yhat.
// Correctness-only path -- speed irrelevant; no spin-waits (deadlock-free).
__global__ __launch_bounds__(256) void fb_all_kernel(
    const float* __restrict__ x, const float* __restrict__ y,
    const float* __restrict__ W1, const float* __restrict__ b1,
    const float* __restrict__ W2, const float* __restrict__ b2,
    float* __restrict__ wsf, float* __restrict__ out)
{
  if (wsf[0] >= 0.5f) return;                     // certified zero path taken
  const int t = threadIdx.x;
  float* fb_part = wsf + 552960;
  float* p_ex    = wsf + 1077248;
  float* Q       = wsf + 1077504;
  float* L       = Q + 65536;
  float* Qe      = L + 65536;
  // phase 1: exact Z^T y partials (32 rows per block)
  {
    const int b0 = blockIdx.x * 32;
    float zty = 0.f;
    for (int r = 0; r < 32; ++r) {
      float xv = x[(size_t)(b0 + r) * NF + t];
      zty = fmaf(zeval(W1, b1, W2, b2, t, xv), y[b0 + r], zty);
    }
    fb_part[(size_t)blockIdx.x * NF + t] = zty;
  }
  __threadfence();
  __shared__ unsigned int tick;
  if (t == 0)
    tick = atomicAdd(reinterpret_cast<unsigned int*>(&wsf[2]), 1u);
  __syncthreads();
  if (tick != 2047u) return;
  // ---- last block: serial completion ----
  {
    float s = 0.f;
    for (int j = 0; j < 2048; ++j) s += fb_part[(size_t)j * NF + t];
    p_ex[t] = ALPHA_BF - s;
  }
  for (int i = t; i < 65536; i += 256)
    Q[i] = ((i >> 8) == (i & 255)) ? JITTERF : 0.f;
  __syncthreads();
  __shared__ float zsh[16 * NF];                  // 16 KiB chunks of Z
  for (int c = 0; c < BATCHN / 16; ++c) {
    const int r0 = c * 16;
    for (int r = 0; r < 16; ++r)
      zsh[r * NF + t] = zeval(W1, b1, W2, b2, t, x[(size_t)(r0 + r) * NF + t]);
    __syncthreads();
    for (int j = 0; j < NF; ++j) {
      float s = 0.f;
      for (int r = 0; r < 16; ++r) s += zsh[r * NF + t] * zsh[r * NF + j];
      Q[t * NF + j] += s;
    }
    __syncthreads();
  }
  // right-looking Cholesky -> Qe = L L^T
  __shared__ float sm[NF];
  __shared__ float lam_s[NF];
  for (int i = 0; i < NF; ++i) L[i * NF + t] = (t <= i) ? Q[i * NF + t] : 0.f;
  __syncthreads();
  for (int k = 0; k < NF; ++k) {
    if (t == 0) L[k * NF + k] = sqrtf(L[k * NF + k]);
    __syncthreads();
    float lkk = L[k * NF + k];
    if (t > k) L[t * NF + k] /= lkk;
    __syncthreads();
    if (t > k) {
      float ltk = L[t * NF + k];
      for (int i = k + 1; i <= t; ++i) L[t * NF + i] -= ltk * L[i * NF + k];
    }
    __syncthreads();
  }
  for (int i = 0; i < NF; ++i) {
    int m = (i < t) ? i : t;
    float s = 0.f;
    for (int k = 0; k <= m; ++k) s += L[i * NF + k] * L[t * NF + k];
    Qe[i * NF + t] = s;
  }
  __syncthreads();
  lam_s[t] = 1.f;
  __syncthreads();
  float lmax = 1.f;
  for (int it = 0; it < 256; ++it) {              // power iteration
    float s = 0.f;
    for (int k = 0; k < NF; ++k) s += Qe[t * NF + k] * lam_s[k];
    sm[t] = s * s;
    __syncthreads();
    for (int off = 128; off > 0; off >>= 1) {
      if (t < off) sm[t] += sm[t + off];
      __syncthreads();
    }
    float nrm = sqrtf(sm[0]);
    __syncthreads();
    lam_s[t] = s / nrm;
    lmax = nrm;
    __syncthreads();
  }
  float step = 1.0f / lmax;
  lam_s[t] = 0.f;
  __syncthreads();
  float pv = p_ex[t];
  for (int it = 0; it < QP_ITERS_N; ++it) {       // projected gradient
    float s = 0.f;
    for (int k = 0; k < NF; ++k) s += Qe[t * NF + k] * lam_s[k];
    float ln = fmaxf(lam_s[t] - step * (s + pv), 0.f);
    __syncthreads();
    lam_s[t] = ln;
    __syncthreads();
  }
  out[BATCHN + t] = lam_s[t];
  __syncthreads();
  for (int b = t; b < BATCHN; b += 256) {         // y_hat = Z @ lam
    float acc = 0.f;
    for (int n = 0; n < NF; ++n)
      acc = fmaf(zeval(W1, b1, W2, b2, n, x[(size_t)b * NF + n]),
                 lam_s[n], acc);
    out[b] = acc;
  }
}

// ---------------- host launcher ---------------------------------------------
extern "C" void kernel_launch(void* const* d_in, const int* in_sizes, int n_in,
                              void* d_out, int out_size, void* d_ws, size_t ws_size,
                              hipStream_t stream) {
  const float* x  = (const float*)d_in[0];
  const float* y  = (const float*)d_in[1];
  const float* W1 = (const float*)d_in[2];
  const float* b1 = (const float*)d_in[3];
  const float* W2 = (const float*)d_in[4];
  const float* b2 = (const float*)d_in[5];
  float* out = (float*)d_out;            // [0,65536): y_hat ; [65536,65792): lam
  float* ws  = (float*)d_ws;

  // fast certified path (4 nodes) + single-node fallback
  mcoeff_kernel<<<1472, 256, 0, stream>>>(y, W1, b1, W2, ws);
  zmom_kernel<<<1024, 256, 0, stream>>>(x, y, ws);
  red1f_kernel<<<64, 256, 0, stream>>>(ws);
  zwflag_kernel<<<257, 256, 0, stream>>>(b2, ws, out);
  fb_all_kernel<<<2048, 256, 0, stream>>>(x, y, W1, b1, W2, b2, ws, out);
}

// Round 24
// 45.746 us; speedup vs baseline: 1.0555x; 1.0555x over previous
//
#include <hip/hip_runtime.h>
#include <math.h>

// DifferentiableLassoSelector: B=65536, n=256, h=32.
// p = 6553.6 - Z^T y > 0 elementwise (~40 sigma margin) => projected-gradient
// QP stays at lam=0 exactly => y_hat = 0 exactly.
// Chebyshev factorization, h pre-combined: C_k[n] = sum_h W2 c_k[n,h];
// z~[b,n] = sum_k C_k T_k(x/X); zty[n] = sum_b y z~.
// FINAL (r21 config, measured 45.9us): LDS-staged zmom decouples load depth
// from the VGPR allocator (r15-r18 showed regalloc serializes VGPR pipelines
// at 32 regs); 1024 blocks x 64 rows, 8-row chunks (2 global_load_lds per
// wave per chunk) amortizes the __syncthreads vmcnt(0) drain; 4 blocks/CU
// cross-cover residual stalls. Quadrant scan r20-r23 confirms this optimum.
// Certification (observed coeff tail) gates the zero path; exact fallback is
// one flag-guarded kernel (last-block-done ticket).

#define NF 256
#define HID 32
#define BATCHN 65536
#define ALPHA_BF 6553.6f               // ALPHA * BATCH
#define JITTERF 1e-4f
#define QP_ITERS_N 500
#define K2C 2.8853900817779268f        // 2*log2(e): exp2(K2C*u) = e^{2u}
#define XFIX 6.5f
#define INVX (1.0f / 6.5f)
#define NNODE 44                       // Chebyshev nodes; coeffs k=0..43
// ws float layout:
// 0: flagA | 1: Xobs bits | 2: ticket | 8..72: ypart[64] | 72..136: yabspart
// 256:     Carr[21][256]     -> 5632
// 5632:    tailpart[23][256] -> 11520
// 11520:   sw2[256]          -> 11776
// 12288:   part2[64][256]    -> 28672
// 28672:   part[1024][256]   -> 290816
// 552960:  fb_part[2048][256]-> 1077248
// 1077248: p_ex[256]         -> 1077504
// 1077504: Q | L | Qe        -> 1274112  (~5.1 MB total)

#if __has_builtin(__builtin_amdgcn_exp2f)
__device__ __forceinline__ float fexp2(float x) { return __builtin_amdgcn_exp2f(x); }
#else
__device__ __forceinline__ float fexp2(float x) { return exp2f(x); }
#endif
#if __has_builtin(__builtin_amdgcn_rcpf)
__device__ __forceinline__ float frcp(float x) { return __builtin_amdgcn_rcpf(x); }
#else
__device__ __forceinline__ float frcp(float x) { return 1.0f / x; }
#endif

// async global->LDS stage of 16B/lane (1KB/wave): LDS dest is wave-uniform,
// HW scatters lane l to ldst + l*16. Fallback: reg-relay with same layout.
#if __has_builtin(__builtin_amdgcn_global_load_lds)
#define STAGE_ROW(gsrc, ldst, lane) \
  __builtin_amdgcn_global_load_lds( \
      (const __attribute__((address_space(1))) void*)(gsrc), \
      (__attribute__((address_space(3))) void*)(ldst), 16, 0, 0)
#else
#define STAGE_ROW(gsrc, ldst, lane) \
  do { *reinterpret_cast<float4*>((float*)(ldst) + (lane) * 4) = \
       *reinterpret_cast<const float4*>(gsrc); } while (0)
#endif

// exact per-feature MLP output z[b,n] (fallback path only; perf-irrelevant)
__device__ __forceinline__ float zeval(const float* __restrict__ W1,
                                       const float* __restrict__ b1,
                                       const float* __restrict__ W2,
                                       const float* __restrict__ b2,
                                       int n, float xv)
{
  float acc = b2[n];
  for (int h = 0; h < HID; ++h) {
    float u  = fmaf(xv, W1[n * HID + h], b1[n * HID + h]);
    float th = fmaf(-2.f, frcp(fexp2(K2C * u) + 1.f), 1.f);   // exact tanh
    acc = fmaf(W2[n * HID + h], th, acc);
  }
  return acc;
}

// ---------------- mcoeff: ysum (blocks 0..63) + combined coeffs (64..1471) ---
__global__ __launch_bounds__(256) void mcoeff_kernel(
    const float* __restrict__ y,
    const float* __restrict__ W1, const float* __restrict__ b1,
    const float* __restrict__ W2, float* __restrict__ wsf)
{
  const int t = threadIdx.x;
  if ((int)blockIdx.x < 64) {
    // ---- ysum role: per-block partial sums of y and |y| ----
    const int gi = blockIdx.x * 256 + t;
    if (gi == 0) wsf[1] = 0.f;                  // Xobs (atomicMax target)
    if (gi == 2) wsf[2] = 0.f;                  // fallback ticket
    float4 v = *reinterpret_cast<const float4*>(y + gi * 4);
    float s  = (v.x + v.y) + (v.z + v.w);
    float sa = (fabsf(v.x) + fabsf(v.y)) + (fabsf(v.z) + fabsf(v.w));
    #pragma unroll
    for (int m = 1; m < 64; m <<= 1) {
      s  += __shfl_xor(s, m);
      sa += __shfl_xor(sa, m);
    }
    __shared__ float ls[4], la[4];
    int w = t >> 6;
    if ((t & 63) == 0) { ls[w] = s; la[w] = sa; }
    __syncthreads();
    if (t == 0) {
      wsf[8  + blockIdx.x] = (ls[0] + ls[1]) + (ls[2] + ls[3]);
      wsf[72 + blockIdx.x] = (la[0] + la[1]) + (la[2] + la[3]);
    }
  } else {
    // ---- coeff role: thread = (id, k); h-reduced combined coefficients ----
    const int cb = blockIdx.x - 64;            // [0, 1408)
    const int k  = cb >> 5;                    // 0..43
    const int id = (cb & 31) * 256 + t;        // 0..8191 = n*32+h
    const int h  = t & 31;
    const int n  = id >> 5;
    const float aX  = W1[id] * XFIX;
    const float bb  = b1[id];
    const float w2v = W2[id];
    const float kf = (float)k;
    const float C1 = (float)(M_PI / (double)NNODE);
    float acc = 0.f;
    #pragma unroll 4
    for (int jn = 0; jn < NNODE; ++jn) {
      float ang = ((float)jn + 0.5f) * C1;
      float tj  = __cosf(ang);
      float u   = fmaf(aX, tj, bb);
      float f   = fmaf(-2.f, frcp(fexp2(K2C * u) + 1.f), 1.f);  // exact tanh
      acc = fmaf(f, __cosf(kf * ang), acc);
    }
    const float ck = acc * ((k == 0) ? (1.0f / (float)NNODE)
                                     : (2.0f / (float)NNODE));
    float comb = w2v * ck;                     // signed, for C_k[n]
    float cabs = fabsf(comb);                  // |W2 c_k|, for tail
    float wabs = fabsf(w2v);                   // |W2|, for k==0 slack
    #pragma unroll
    for (int m = 1; m < 32; m <<= 1) {         // reduce over h (32 lanes)
      comb += __shfl_xor(comb, m);
      cabs += __shfl_xor(cabs, m);
      wabs += __shfl_xor(wabs, m);
    }
    if (h == 0) {
      if (k <= 20) wsf[256 + k * 256 + n] = comb;
      else         wsf[5632 + (k - 21) * 256 + n] = cabs;
      if (k == 0)  wsf[11520 + n] = wabs;
    }
  }
}

// ---------------- zmom: LDS-staged, 8-row chunks, 1024 blocks x 64 rows ------
#define STEP1(CK) { float q = fmaf(dd, Tc, -Tm); \
  a = fmaf(CK, q, a); Tm = Tc; Tc = q; }

__global__ __launch_bounds__(256, 4) void zmom_kernel(
    const float* __restrict__ x, const float* __restrict__ y,
    float* __restrict__ wsf)
{
  const int t = threadIdx.x;                // feature n == t
  const int lane = t & 63, wv = t >> 6;
  __shared__ float xbuf[2][8][NF];          // 16 KB: 2 bufs x 8 rows x 1KB
  const float* Carr = wsf + 256;
  const float c00 = Carr[t],            c01 = Carr[256 + t];
  const float c02 = Carr[512 + t],      c03 = Carr[768 + t];
  const float c04 = Carr[1024 + t],     c05 = Carr[1280 + t];
  const float c06 = Carr[1536 + t],     c07 = Carr[1792 + t];
  const float c08 = Carr[2048 + t],     c09 = Carr[2304 + t];
  const float c10 = Carr[2560 + t],     c11 = Carr[2816 + t];
  const float c12 = Carr[3072 + t],     c13 = Carr[3328 + t];
  const float c14 = Carr[3584 + t],     c15 = Carr[3840 + t];
  const float c16 = Carr[4096 + t],     c17 = Carr[4352 + t];
  const float c18 = Carr[4608 + t],     c19 = Carr[4864 + t];
  const float c20 = Carr[5120 + t];
  const int b0 = blockIdx.x * 64;           // 1024 blocks x 64 rows
  // prologue: wave wv stages rows {2wv, 2wv+1} of chunk 0 (2 instr = 2KB)
  STAGE_ROW(x + (size_t)(b0 + 2 * wv) * NF + lane * 4,
            &xbuf[0][2 * wv][0], lane);
  STAGE_ROW(x + (size_t)(b0 + 2 * wv + 1) * NF + lane * 4,
            &xbuf[0][2 * wv + 1][0], lane);
  __syncthreads();                          // drains vmcnt -> buf0 ready
  float z0 = 0.f, mx = 0.f;
  for (int c = 0; c < 8; ++c) {             // 8 chunks x 8 rows
    if (c < 7) {
      const int r0 = b0 + (c + 1) * 8 + 2 * wv;
      STAGE_ROW(x + (size_t)r0 * NF + lane * 4,
                &xbuf[(c + 1) & 1][2 * wv][0], lane);
      STAGE_ROW(x + (size_t)(r0 + 1) * NF + lane * 4,
                &xbuf[(c + 1) & 1][2 * wv + 1][0], lane);
    }
    const float* xb = &xbuf[c & 1][0][0];
    const float* yb = y + b0 + c * 8;
    #pragma unroll
    for (int r = 0; r < 8; ++r) {           // 8 independent rows (ILP)
      float xv = xb[r * NF + t];            // ds_read, 2-way bank = free
      float yv = yb[r];                     // uniform -> scalar load
      mx = fmaxf(mx, fabsf(xv));
      float h = xv * INVX;
      float dd = h + h;
      float Tm = 1.f, Tc = h;
      float a = fmaf(c01, h, c00);
      STEP1(c02) STEP1(c03) STEP1(c04) STEP1(c05) STEP1(c06) STEP1(c07)
      STEP1(c08) STEP1(c09) STEP1(c10) STEP1(c11) STEP1(c12) STEP1(c13)
      STEP1(c14) STEP1(c15) STEP1(c16) STEP1(c17) STEP1(c18) STEP1(c19)
      STEP1(c20)
      z0 = fmaf(a, yv, z0);
    }
    __syncthreads();                        // drains next-chunk stage + sync
  }
  // |x| max: wave-reduce, block-reduce, ONE atomic per block (order-exact)
  #pragma unroll
  for (int m = 1; m < 64; m <<= 1) mx = fmaxf(mx, __shfl_xor(mx, m));
  __shared__ float wmx[4];
  if (lane == 0) wmx[wv] = mx;
  __syncthreads();
  if (t == 0) {
    float m4 = fmaxf(fmaxf(wmx[0], wmx[1]), fmaxf(wmx[2], wmx[3]));
    atomicMax(reinterpret_cast<unsigned int*>(&wsf[1]), __float_as_uint(m4));
  }
  wsf[28672 + (size_t)blockIdx.x * NF + t] = z0;  // coalesced 1KB/blk
}

// ---------------- red1f: part[1024][256] -> part2[64][256] -------------------
__global__ __launch_bounds__(256) void red1f_kernel(float* __restrict__ wsf)
{
  const int n = threadIdx.x, j = blockIdx.x;      // 64 blocks x 16 slices
  const float* p = wsf + 28672 + (size_t)j * 16 * NF + n;
  float s0 = 0.f, s1 = 0.f, s2 = 0.f, s3 = 0.f;
  #pragma unroll
  for (int k = 0; k < 16; k += 4) {
    s0 += p[(size_t)k * NF];       s1 += p[(size_t)(k + 1) * NF];
    s2 += p[(size_t)(k + 2) * NF]; s3 += p[(size_t)(k + 3) * NF];
  }
  wsf[12288 + (size_t)j * NF + n] = (s0 + s1) + (s2 + s3);
}

// ---------------- zwflag: redundant flag computation + zero-write ------------
__global__ __launch_bounds__(256) void zwflag_kernel(
    const float* __restrict__ b2, float* __restrict__ wsf,
    float* __restrict__ out)
{
  const int t = threadIdx.x;                      // t == feature n
  __shared__ float shv[2];
  if (t < 64) {
    float a = wsf[8 + t], bb = wsf[72 + t];
    #pragma unroll
    for (int m = 1; m < 64; m <<= 1) {
      a  += __shfl_xor(a, m);
      bb += __shfl_xor(bb, m);
    }
    if (t == 0) { shv[0] = a; shv[1] = bb; }
  }
  __syncthreads();
  const float Sy = shv[0], SyA = shv[1];
  float s = 0.f;
  #pragma unroll
  for (int j = 0; j < 64; ++j) s += wsf[12288 + j * NF + t];
  float tailn = 0.f;
  #pragma unroll
  for (int q = 0; q < 23; ++q) tailn += wsf[5632 + q * 256 + t];
  float ptil = ALPHA_BF - (s + b2[t] * Sy);
  float cert = fmaf(fmaf(3.0f, tailn, 3e-3f * wsf[11520 + t]), SyA, 128.0f);
  int ok = ((ptil - cert) >= 0.f) ? 1 : 0;        // NaN -> 0
  __shared__ int smi[256];
  __shared__ int okk;
  smi[t] = ok;
  __syncthreads();
  for (int off = 128; off > 0; off >>= 1) {
    if (t < off) smi[t] = smi[t] & smi[t + off];
    __syncthreads();
  }
  if (t == 0) {
    float Xo = __uint_as_float(*reinterpret_cast<unsigned int*>(&wsf[1]));
    okk = (smi[0] && (Xo <= XFIX)) ? 1 : 0;
    if (blockIdx.x == 0) wsf[0] = okk ? 1.f : 0.f;   // flag for fallback
  }
  __syncthreads();
  if (!okk) return;
  int i = blockIdx.x * 256 + t;                   // 257 blocks = 65792 exactly
  if (i < BATCHN + NF) out[i] = 0.f;              // exact zeros
}

// ---------------- fb_all: entire exact fallback in ONE node ------------------
// flag==1 (always, for bench inputs): every block exits immediately.
// flag==0: 2048 blocks compute exact zty partials; the LAST block to finish
// (device-scope ticket) serially completes p, Q, Cholesky, QP, yhat.
// Correctness-only path -- speed irrelevant; no spin-waits (deadlock-free).
__global__ __launch_bounds__(256) void fb_all_kernel(
    const float* __restrict__ x, const float* __restrict__ y,
    const float* __restrict__ W1, const float* __restrict__ b1,
    const float* __restrict__ W2, const float* __restrict__ b2,
    float* __restrict__ wsf, float* __restrict__ out)
{
  if (wsf[0] >= 0.5f) return;                     // certified zero path taken
  const int t = threadIdx.x;
  float* fb_part = wsf + 552960;
  float* p_ex    = wsf + 1077248;
  float* Q       = wsf + 1077504;
  float* L       = Q + 65536;
  float* Qe      = L + 65536;
  // phase 1: exact Z^T y partials (32 rows per block)
  {
    const int b0 = blockIdx.x * 32;
    float zty = 0.f;
    for (int r = 0; r < 32; ++r) {
      float xv = x[(size_t)(b0 + r) * NF + t];
      zty = fmaf(zeval(W1, b1, W2, b2, t, xv), y[b0 + r], zty);
    }
    fb_part[(size_t)blockIdx.x * NF + t] = zty;
  }
  __threadfence();
  __shared__ unsigned int tick;
  if (t == 0)
    tick = atomicAdd(reinterpret_cast<unsigned int*>(&wsf[2]), 1u);
  __syncthreads();
  if (tick != 2047u) return;
  // ---- last block: serial completion ----
  {
    float s = 0.f;
    for (int j = 0; j < 2048; ++j) s += fb_part[(size_t)j * NF + t];
    p_ex[t] = ALPHA_BF - s;
  }
  for (int i = t; i < 65536; i += 256)
    Q[i] = ((i >> 8) == (i & 255)) ? JITTERF : 0.f;
  __syncthreads();
  __shared__ float zsh[16 * NF];                  // 16 KiB chunks of Z
  for (int c = 0; c < BATCHN / 16; ++c) {
    const int r0 = c * 16;
    for (int r = 0; r < 16; ++r)
      zsh[r * NF + t] = zeval(W1, b1, W2, b2, t, x[(size_t)(r0 + r) * NF + t]);
    __syncthreads();
    for (int j = 0; j < NF; ++j) {
      float s = 0.f;
      for (int r = 0; r < 16; ++r) s += zsh[r * NF + t] * zsh[r * NF + j];
      Q[t * NF + j] += s;
    }
    __syncthreads();
  }
  // right-looking Cholesky -> Qe = L L^T
  __shared__ float sm[NF];
  __shared__ float lam_s[NF];
  for (int i = 0; i < NF; ++i) L[i * NF + t] = (t <= i) ? Q[i * NF + t] : 0.f;
  __syncthreads();
  for (int k = 0; k < NF; ++k) {
    if (t == 0) L[k * NF + k] = sqrtf(L[k * NF + k]);
    __syncthreads();
    float lkk = L[k * NF + k];
    if (t > k) L[t * NF + k] /= lkk;
    __syncthreads();
    if (t > k) {
      float ltk = L[t * NF + k];
      for (int i = k + 1; i <= t; ++i) L[t * NF + i] -= ltk * L[i * NF + k];
    }
    __syncthreads();
  }
  for (int i = 0; i < NF; ++i) {
    int m = (i < t) ? i : t;
    float s = 0.f;
    for (int k = 0; k <= m; ++k) s += L[i * NF + k] * L[t * NF + k];
    Qe[i * NF + t] = s;
  }
  __syncthreads();
  lam_s[t] = 1.f;
  __syncthreads();
  float lmax = 1.f;
  for (int it = 0; it < 256; ++it) {              // power iteration
    float s = 0.f;
    for (int k = 0; k < NF; ++k) s += Qe[t * NF + k] * lam_s[k];
    sm[t] = s * s;
    __syncthreads();
    for (int off = 128; off > 0; off >>= 1) {
      if (t < off) sm[t] += sm[t + off];
      __syncthreads();
    }
    float nrm = sqrtf(sm[0]);
    __syncthreads();
    lam_s[t] = s / nrm;
    lmax = nrm;
    __syncthreads();
  }
  float step = 1.0f / lmax;
  lam_s[t] = 0.f;
  __syncthreads();
  float pv = p_ex[t];
  for (int it = 0; it < QP_ITERS_N; ++it) {       // projected gradient
    float s = 0.f;
    for (int k = 0; k < NF; ++k) s += Qe[t * NF + k] * lam_s[k];
    float ln = fmaxf(lam_s[t] - step * (s + pv), 0.f);
    __syncthreads();
    lam_s[t] = ln;
    __syncthreads();
  }
  out[BATCHN + t] = lam_s[t];
  __syncthreads();
  for (int b = t; b < BATCHN; b += 256) {         // y_hat = Z @ lam
    float acc = 0.f;
    for (int n = 0; n < NF; ++n)
      acc = fmaf(zeval(W1, b1, W2, b2, n, x[(size_t)b * NF + n]),
                 lam_s[n], acc);
    out[b] = acc;
  }
}

// ---------------- host launcher ---------------------------------------------
extern "C" void kernel_launch(void* const* d_in, const int* in_sizes, int n_in,
                              void* d_out, int out_size, void* d_ws, size_t ws_size,
                              hipStream_t stream) {
  const float* x  = (const float*)d_in[0];
  const float* y  = (const float*)d_in[1];
  const float* W1 = (const float*)d_in[2];
  const float* b1 = (const float*)d_in[3];
  const float* W2 = (const float*)d_in[4];
  const float* b2 = (const float*)d_in[5];
  float* out = (float*)d_out;            // [0,65536): y_hat ; [65536,65792): lam
  float* ws  = (float*)d_ws;

  // fast certified path (4 nodes) + single-node fallback
  mcoeff_kernel<<<1472, 256, 0, stream>>>(y, W1, b1, W2, ws);
  zmom_kernel<<<1024, 256, 0, stream>>>(x, y, ws);
  red1f_kernel<<<64, 256, 0, stream>>>(ws);
  zwflag_kernel<<<257, 256, 0, stream>>>(b2, ws, out);
  fb_all_kernel<<<2048, 256, 0, stream>>>(x, y, W1, b1, W2, b2, ws, out);
}